// Round 16
// baseline (2814.952 us; speedup 1.0000x reference)
//
#include <hip/hip_runtime.h>
#include <hip/hip_bf16.h>
#include <math.h>

namespace {
constexpr int V = 32000, D = 1024, L = 8, H = 16, T = 128, F = 2816, DH = 64;
constexpr float EPS = 1e-5f;
constexpr float SCALE = 0.125f; // 1/sqrt(DH)
constexpr int QKVN = 3 * D;     // 3072
constexpr int GUN  = 2 * F;     // 5632
constexpr int NP_Q = 8;         // QKV split-K chunks (CH=128)
constexpr int NP_O = 8;         // O-proj chunks (CH=128)
constexpr int NP_G = 8;         // GU chunks (CH=128)
constexpr int NP_D = 22;        // Wd chunks (K=2816 = 22*128)
constexpr int NGRP_Q = 48;      // QKV epilogue groups (z*16+ct)
constexpr int NGRP_G = 44;      // GU epilogue groups (ct)
}

typedef __attribute__((ext_vector_type(8))) short short8;
typedef __attribute__((ext_vector_type(4))) float f32x4;

__device__ __forceinline__ unsigned short f2bf(float x) {
    union { float f; unsigned u; } v; v.f = x;
    unsigned r = v.u + 0x7FFFu + ((v.u >> 16) & 1u);
    return (unsigned short)(r >> 16);
}

// ---------------- Embedding gather + RoPE tables (fused) ----------------
__global__ void embed_rope_kernel(const int* __restrict__ ids, const float* __restrict__ emb,
                                  float* __restrict__ X,
                                  float* __restrict__ cosT, float* __restrict__ sinT) {
    int t = blockIdx.x, tid = threadIdx.x;
    int id = ids[t];
    ((float4*)(X + (size_t)t * D))[tid] = ((const float4*)(emb + (size_t)id * D))[tid];
    if (tid < 32) {
        float inv = powf(10000.0f, -(2.0f * (float)tid) / (float)DH);
        float ang = (float)t * inv;
        cosT[t * 32 + tid] = cosf(ang);
        sinT[t * 32 + tid] = sinf(ang);
    }
}

// ---------------- RMSNorm + unrolled partial-sum residual update ----------------
template<int NP, bool BF16OUT>
__launch_bounds__(256)
__global__ void rmsnorm_sum_kernel(float* __restrict__ X, const float* __restrict__ P,
                                   const float* __restrict__ w, void* __restrict__ Y) {
    int t = blockIdx.x, tid = threadIdx.x;
    float4 xv = ((float4*)(X + (size_t)t * D))[tid];
    #pragma unroll
    for (int c = 0; c < NP; ++c) {
        float4 pv = ((const float4*)(P + ((size_t)c * T + t) * D))[tid];
        xv.x += pv.x; xv.y += pv.y; xv.z += pv.z; xv.w += pv.w;
    }
    if (NP) ((float4*)(X + (size_t)t * D))[tid] = xv;
    float s = xv.x * xv.x + xv.y * xv.y + xv.z * xv.z + xv.w * xv.w;
    for (int o = 32; o >= 1; o >>= 1) s += __shfl_xor(s, o);
    __shared__ float red[4];
    if ((tid & 63) == 0) red[tid >> 6] = s;
    __syncthreads();
    float tot = red[0] + red[1] + red[2] + red[3];
    float r = rsqrtf(tot / (float)D + EPS);
    float4 wv = ((const float4*)w)[tid];
    if (BF16OUT) {
        ushort4 y;
        y.x = f2bf(xv.x * r * wv.x); y.y = f2bf(xv.y * r * wv.y);
        y.z = f2bf(xv.z * r * wv.z); y.w = f2bf(xv.w * r * wv.w);
        ((ushort4*)((unsigned short*)Y + (size_t)t * D))[tid] = y;
    } else {
        float4 y;
        y.x = xv.x * r * wv.x; y.y = xv.y * r * wv.y;
        y.z = xv.z * r * wv.z; y.w = xv.w * r * wv.w;
        ((float4*)((float*)Y + (size_t)t * D))[tid] = y;
    }
}

// ---------------- GEMM body: 64-col x 128-k tile, fp32 [K][N] weights ----------------
// (round-11/14 proven) 512 threads / 8 waves: wave = (M-half mh) x (col-group cg).
__device__ __forceinline__ void gemm_body(const unsigned short* __restrict__ A, int lda,
                                          const float* __restrict__ W, int ldw,
                                          int n0, int k0,
                                          float* __restrict__ outP, int ldo, int outcol0,
                                          unsigned short* Bst) {
    constexpr int LSTR = 136;
    const int tid = threadIdx.x;
    const int wave = tid >> 6, lane = tid & 63;
    const int cg = wave & 3, mh = wave >> 2;
    const int sc = tid & 63;
    const int so = tid >> 6;  // 0..7
    const float* wCol = W + (size_t)k0 * ldw + n0 + sc;
    unsigned short* wp = Bst + sc * LSTR;
    const int lrow = lane & 15;
    const int lqo = lane >> 4;
    const unsigned short* aB = A + (size_t)(mh * 64 + lrow) * lda + k0 + lqo * 8;
    const unsigned short* bRd = Bst + (cg * 16 + lrow) * LSTR + lqo * 8;
    float pre[16];
    #pragma unroll
    for (int p = 0; p < 2; ++p) {
        const float* src = wCol + (size_t)((so * 2 + p) * 8) * ldw;
        #pragma unroll
        for (int j = 0; j < 8; ++j) pre[p * 8 + j] = src[(size_t)j * ldw];
    }
    #pragma unroll
    for (int p = 0; p < 2; ++p) {
        short8 bv;
        #pragma unroll
        for (int j = 0; j < 8; ++j) bv[j] = (short)f2bf(pre[p * 8 + j]);
        *(short8*)(wp + (so * 2 + p) * 8) = bv;
    }
    __syncthreads();
    f32x4 acc[4] = {};
    #pragma unroll
    for (int ks = 0; ks < 4; ++ks) {
        short8 b = *(const short8*)(bRd + ks * 32);
        #pragma unroll
        for (int mf = 0; mf < 4; ++mf) {
            short8 a = *(const short8*)(aB + (size_t)(mf * 16) * lda + ks * 32);
            acc[mf] = __builtin_amdgcn_mfma_f32_16x16x32_bf16(a, b, acc[mf], 0, 0, 0);
        }
    }
    const int col = outcol0 + cg * 16 + lrow;
    #pragma unroll
    for (int mf = 0; mf < 4; ++mf) {
        int r0 = mh * 64 + mf * 16 + lqo * 4;
        #pragma unroll
        for (int r = 0; r < 4; ++r)
            outP[(size_t)(r0 + r) * ldo + col] = acc[mf][r];
    }
}

// ---------------- plain split-K GEMM (O-proj, Wd) ----------------
__launch_bounds__(512)
__global__ void gemm64_kernel(const unsigned short* __restrict__ A, int lda,
                              const float* __restrict__ W, int ldw,
                              float* __restrict__ out, int ldo, size_t chunkStride) {
    __shared__ unsigned short Bst[64 * 136];
    gemm_body(A, lda, W, ldw, blockIdx.x * 64, blockIdx.y * 128,
              out + blockIdx.y * chunkStride, ldo, blockIdx.x * 64, Bst);
}

// ---------------- QKV GEMM + counter-elected rope epilogue ----------------
// Group (z,ct): 8 k-chunk blocks. Last arriver reduces the 8 partials for its
// 64 cols x 128 rows, applies RoPE, writes Qr / KrT (transposed) / Vr.
__launch_bounds__(512)
__global__ void gemm_qkv_rope_kernel(const unsigned short* __restrict__ A,
                                     const float* __restrict__ Wq, const float* __restrict__ Wk,
                                     const float* __restrict__ Wv,
                                     float* __restrict__ P0,
                                     const float* __restrict__ cosT,
                                     const float* __restrict__ sinT,
                                     float* __restrict__ Qr, float* __restrict__ KrT,
                                     float* __restrict__ Vr,
                                     unsigned* __restrict__ cnt) {
    __shared__ unsigned short Bst[64 * 136];
    const int z = blockIdx.z, ct = blockIdx.x, kc = blockIdx.y;
    const float* W = z == 0 ? Wq : (z == 1 ? Wk : Wv);
    gemm_body(A, D, W, D, ct * 64, kc * 128, P0 + (size_t)kc * T * QKVN, QKVN,
              z * D + ct * 64, Bst);
    // election: arrival-only counter (no spin -> no deadlock)
    __syncthreads();
    __threadfence();
    __shared__ unsigned prevS;
    if (threadIdx.x == 0)
        prevS = __hip_atomic_fetch_add(&cnt[z * 16 + ct], 1u, __ATOMIC_ACQ_REL,
                                       __HIP_MEMORY_SCOPE_AGENT);
    __syncthreads();
    if (prevS != NP_Q - 1) return;
    __threadfence();
    // epilogue: thread -> (row t, 8-col strip d0 in [0,32))
    const int tid = threadIdx.x;
    const int t = tid >> 2, s = tid & 3;
    const int cbase = z * D + ct * 64;
    const int d0 = s * 8;
    float lo[8] = {}, hi[8] = {};
    for (int c = 0; c < NP_Q; ++c) {
        const float* b = P0 + ((size_t)c * T + t) * QKVN + cbase + d0;
        float4 a0 = *(const float4*)(b);
        float4 a1 = *(const float4*)(b + 4);
        float4 b0 = *(const float4*)(b + 32);
        float4 b1 = *(const float4*)(b + 36);
        lo[0] += a0.x; lo[1] += a0.y; lo[2] += a0.z; lo[3] += a0.w;
        lo[4] += a1.x; lo[5] += a1.y; lo[6] += a1.z; lo[7] += a1.w;
        hi[0] += b0.x; hi[1] += b0.y; hi[2] += b0.z; hi[3] += b0.w;
        hi[4] += b1.x; hi[5] += b1.y; hi[6] += b1.z; hi[7] += b1.w;
    }
    const int h = ct;  // head index (valid for z=0,1)
    if (z == 2) {
        float* vb = Vr + (size_t)t * D + ct * 64 + d0;
        float4 v;
        v.x = lo[0]; v.y = lo[1]; v.z = lo[2]; v.w = lo[3]; *(float4*)(vb) = v;
        v.x = lo[4]; v.y = lo[5]; v.z = lo[6]; v.w = lo[7]; *(float4*)(vb + 4) = v;
        v.x = hi[0]; v.y = hi[1]; v.z = hi[2]; v.w = hi[3]; *(float4*)(vb + 32) = v;
        v.x = hi[4]; v.y = hi[5]; v.z = hi[6]; v.w = hi[7]; *(float4*)(vb + 36) = v;
        return;
    }
    float ro[8], rh[8];
    #pragma unroll
    for (int i = 0; i < 8; ++i) {
        int d = d0 + i;
        float cc = cosT[t * 32 + d], sn = sinT[t * 32 + d];
        ro[i] = lo[i] * cc - hi[i] * sn;
        rh[i] = hi[i] * cc + lo[i] * sn;
    }
    if (z == 0) {
        float* qb = Qr + (size_t)t * D + h * DH + d0;
        float4 v;
        v.x = ro[0]; v.y = ro[1]; v.z = ro[2]; v.w = ro[3]; *(float4*)(qb) = v;
        v.x = ro[4]; v.y = ro[5]; v.z = ro[6]; v.w = ro[7]; *(float4*)(qb + 4) = v;
        v.x = rh[0]; v.y = rh[1]; v.z = rh[2]; v.w = rh[3]; *(float4*)(qb + 32) = v;
        v.x = rh[4]; v.y = rh[5]; v.z = rh[6]; v.w = rh[7]; *(float4*)(qb + 36) = v;
    } else {
        #pragma unroll
        for (int i = 0; i < 8; ++i) {
            int d = d0 + i;
            KrT[(size_t)(h * DH + d) * T + t] = ro[i];
            KrT[(size_t)(h * DH + d + 32) * T + t] = rh[i];
        }
    }
}

// ---------------- GU GEMM + counter-elected silu epilogue ----------------
// Group ct: 16 blocks (z in {g,u} x 8 k-chunks). Last arriver reduces g,u
// partials for its 64 f-cols x 128 rows and writes silu(g)*u -> Gact bf16.
__launch_bounds__(512)
__global__ void gemm_gu_silu_kernel(const unsigned short* __restrict__ A,
                                    const float* __restrict__ Wg, const float* __restrict__ Wu,
                                    float* __restrict__ P3,
                                    unsigned short* __restrict__ Gact,
                                    unsigned* __restrict__ cnt) {
    __shared__ unsigned short Bst[64 * 136];
    const int z = blockIdx.z, ct = blockIdx.x, kc = blockIdx.y;
    const float* W = z ? Wu : Wg;
    gemm_body(A, D, W, F, ct * 64, kc * 128, P3 + (size_t)kc * T * GUN, GUN,
              z * F + ct * 64, Bst);
    __syncthreads();
    __threadfence();
    __shared__ unsigned prevS;
    if (threadIdx.x == 0)
        prevS = __hip_atomic_fetch_add(&cnt[ct], 1u, __ATOMIC_ACQ_REL,
                                       __HIP_MEMORY_SCOPE_AGENT);
    __syncthreads();
    if (prevS != 2 * NP_G - 1) return;
    __threadfence();
    const int tid = threadIdx.x;
    const int t = tid >> 2, s = tid & 3;
    const int f0 = ct * 64 + s * 16;
    float g[16] = {}, u[16] = {};
    for (int c = 0; c < NP_G; ++c) {
        const float* base = P3 + ((size_t)c * T + t) * GUN;
        #pragma unroll
        for (int q = 0; q < 4; ++q) {
            float4 gv = *(const float4*)(base + f0 + q * 4);
            float4 uv = *(const float4*)(base + F + f0 + q * 4);
            g[q * 4 + 0] += gv.x; g[q * 4 + 1] += gv.y;
            g[q * 4 + 2] += gv.z; g[q * 4 + 3] += gv.w;
            u[q * 4 + 0] += uv.x; u[q * 4 + 1] += uv.y;
            u[q * 4 + 2] += uv.z; u[q * 4 + 3] += uv.w;
        }
    }
    unsigned short* gb = Gact + (size_t)t * F + f0;
    #pragma unroll
    for (int q = 0; q < 4; ++q) {
        ushort4 y;
        float g0 = g[q * 4 + 0], g1 = g[q * 4 + 1], g2 = g[q * 4 + 2], g3 = g[q * 4 + 3];
        y.x = f2bf(g0 / (1.f + __expf(-g0)) * u[q * 4 + 0]);
        y.y = f2bf(g1 / (1.f + __expf(-g1)) * u[q * 4 + 1]);
        y.z = f2bf(g2 / (1.f + __expf(-g2)) * u[q * 4 + 2]);
        y.w = f2bf(g3 / (1.f + __expf(-g3)) * u[q * 4 + 3]);
        *(ushort4*)(gb + q * 4) = y;
    }
}

// ---------------- Causal attention: 4 heads/block, K^T scores, deep-ILP PV ----------------
__launch_bounds__(256)
__global__ void attn_kernel(const float* __restrict__ Q, const float* __restrict__ KrT,
                            const float* __restrict__ Vc, unsigned short* __restrict__ AO) {
    int t = blockIdx.x;
    int wave = threadIdx.x >> 6, lane = threadIdx.x & 63;
    int h = blockIdx.y * 4 + wave;
    __shared__ float qs[4][64];
    __shared__ float ps[4][128];
    float* q = qs[wave];
    float* p = ps[wave];
    q[lane] = Q[(size_t)t * D + h * DH + lane];
    __syncthreads();
    int j0 = lane, j1 = lane + 64;
    const float* kr = KrT + (size_t)h * DH * T;
    float s0a = 0.f, s0b = 0.f, s0c = 0.f, s0d = 0.f;
    float s1a = 0.f, s1b = 0.f, s1c = 0.f, s1d = 0.f;
    #pragma unroll
    for (int d = 0; d < 16; ++d) {
        const float* r0 = kr + (size_t)d * T;
        const float* r1 = kr + (size_t)(d + 16) * T;
        const float* r2 = kr + (size_t)(d + 32) * T;
        const float* r3 = kr + (size_t)(d + 48) * T;
        s0a = fmaf(q[d],      r0[j0], s0a);
        s0b = fmaf(q[d + 16], r1[j0], s0b);
        s0c = fmaf(q[d + 32], r2[j0], s0c);
        s0d = fmaf(q[d + 48], r3[j0], s0d);
        s1a = fmaf(q[d],      r0[j1], s1a);
        s1b = fmaf(q[d + 16], r1[j1], s1b);
        s1c = fmaf(q[d + 32], r2[j1], s1c);
        s1d = fmaf(q[d + 48], r3[j1], s1d);
    }
    float s0 = (s0a + s0b) + (s0c + s0d);
    float s1 = (s1a + s1b) + (s1c + s1d);
    s0 = (j0 <= t) ? s0 * SCALE : -1e30f;
    s1 = (j1 <= t) ? s1 * SCALE : -1e30f;
    float m = fmaxf(s0, s1);
    for (int o = 32; o >= 1; o >>= 1) m = fmaxf(m, __shfl_xor(m, o));
    float e0 = (j0 <= t) ? __expf(s0 - m) : 0.f;
    float e1 = (j1 <= t) ? __expf(s1 - m) : 0.f;
    float sum = e0 + e1;
    for (int o = 32; o >= 1; o >>= 1) sum += __shfl_xor(sum, o);
    float inv = 1.f / sum;
    p[j0] = e0 * inv;   // p[j] = 0 for j > t -> fixed-trip PV exact
    p[j1] = e1 * inv;
    __syncthreads();
    const float* vcol = Vc + h * DH + lane;
    float a[8] = {};
    #pragma unroll
    for (int j = 0; j < T; j += 8)
        #pragma unroll
        for (int u = 0; u < 8; ++u)
            a[u] = fmaf(p[j + u], vcol[(size_t)(j + u) * D], a[u]);
    float r01 = (a[0] + a[1]) + (a[2] + a[3]);
    float r23 = (a[4] + a[5]) + (a[6] + a[7]);
    AO[(size_t)t * D + h * DH + lane] = f2bf(r01 + r23);
}

// ---------------- logits: out[v] = emb[v,:] . xl ----------------
__global__ void logits_kernel(const float* __restrict__ emb, const float* __restrict__ xl,
                              float* __restrict__ out) {
    __shared__ float x[D];
    int tid = threadIdx.x;
    ((float4*)x)[tid] = ((const float4*)xl)[tid];
    __syncthreads();
    int row = blockIdx.x * 4 + (tid >> 6);
    int lane = tid & 63;
    const float4* e4 = (const float4*)(emb + (size_t)row * D);
    const float4* x4 = (const float4*)x;
    float s = 0.f;
    #pragma unroll
    for (int k = lane; k < D / 4; k += 64) {
        float4 ev = e4[k], xv = x4[k];
        s += ev.x * xv.x + ev.y * xv.y + ev.z * xv.z + ev.w * xv.w;
    }
    for (int o = 32; o >= 1; o >>= 1) s += __shfl_xor(s, o);
    if (lane == 0) out[row] = s;
}

extern "C" void kernel_launch(void* const* d_in, const int* in_sizes, int n_in,
                              void* d_out, int out_size, void* d_ws, size_t ws_size,
                              hipStream_t stream) {
    const int*   ids = (const int*)d_in[0];
    const float* emb = (const float*)d_in[1];
    const float* Wq  = (const float*)d_in[2];
    const float* Wk  = (const float*)d_in[3];
    const float* Wv  = (const float*)d_in[4];
    const float* Wo  = (const float*)d_in[5];
    const float* Wg  = (const float*)d_in[6];
    const float* Wu  = (const float*)d_in[7];
    const float* Wd  = (const float*)d_in[8];
    const float* attn_norm = (const float*)d_in[9];
    const float* ffn_norm  = (const float*)d_in[10];
    const float* norm_out  = (const float*)d_in[11];
    float* out = (float*)d_out;

    size_t off = 0;
    auto alloc = [&](size_t bytes) {
        void* p = (char*)d_ws + off;
        off += (bytes + 255) & ~(size_t)255;
        return p;
    };
    unsigned*       cnt   = (unsigned*)alloc((size_t)L * (NGRP_Q + NGRP_G) * 4);
    float*          X     = (float*)alloc((size_t)T * D * 4);
    float*          P0    = (float*)alloc((size_t)NP_Q * T * QKVN * 4);  // QKV partials
    float*          P1    = (float*)alloc((size_t)NP_O * T * D * 4);     // O-proj partials
    float*          P2    = (float*)alloc((size_t)NP_D * T * D * 4);     // Wd partials
    float*          P3    = (float*)alloc((size_t)NP_G * T * GUN * 4);   // GU partials
    float*          Qr    = (float*)alloc((size_t)T * D * 4);
    float*          KrT   = (float*)alloc((size_t)T * D * 4);
    float*          Vr    = (float*)alloc((size_t)T * D * 4);
    float*          cosT  = (float*)alloc((size_t)T * 32 * 4);
    float*          sinT  = (float*)alloc((size_t)T * 32 * 4);
    float*          xl    = (float*)alloc((size_t)D * 4);
    unsigned short* Hn_bf = (unsigned short*)alloc((size_t)T * D * 2);
    unsigned short* AO_bf = (unsigned short*)alloc((size_t)T * D * 2);
    unsigned short* Gact  = (unsigned short*)alloc((size_t)T * F * 2);
    (void)ws_size;

    // epilogue-election counters: zeroed once per call (graph-captured)
    hipMemsetAsync(cnt, 0, (size_t)L * (NGRP_Q + NGRP_G) * 4, stream);
    embed_rope_kernel<<<T, 256, 0, stream>>>(ids, emb, X, cosT, sinT);

    for (int l = 0; l < L; ++l) {
        const float* wq = Wq + (size_t)l * D * D;
        const float* wk = Wk + (size_t)l * D * D;
        const float* wv = Wv + (size_t)l * D * D;
        const float* wo = Wo + (size_t)l * D * D;
        const float* wg = Wg + (size_t)l * D * F;
        const float* wu = Wu + (size_t)l * D * F;
        const float* wd = Wd + (size_t)l * F * D;
        unsigned* cntQ = cnt + (size_t)l * (NGRP_Q + NGRP_G);
        unsigned* cntG = cntQ + NGRP_Q;

        // X += prev Wd partials; Hn = rmsnorm(X)*attn_norm (bf16)
        if (l == 0)
            rmsnorm_sum_kernel<0, true><<<T, 256, 0, stream>>>(
                X, P2, attn_norm + (size_t)l * D, Hn_bf);
        else
            rmsnorm_sum_kernel<NP_D, true><<<T, 256, 0, stream>>>(
                X, P2, attn_norm + (size_t)l * D, Hn_bf);
        // QKV + rope epilogue: 384 blocks, last block per (z,ct) reduces+ropes
        gemm_qkv_rope_kernel<<<dim3(D / 64, NP_Q, 3), 512, 0, stream>>>(
            Hn_bf, wq, wk, wv, P0, cosT, sinT, Qr, KrT, Vr, cntQ);
        // attention: 4 heads/block, K^T coalesced scores, deep-ILP PV -> 512 blocks
        attn_kernel<<<dim3(T, H / 4), 256, 0, stream>>>(Qr, KrT, Vr, AO_bf);
        // O-proj partials: K=1024 split 8x128 -> 128 blocks x 8 waves
        gemm64_kernel<<<dim3(D / 64, NP_O), 512, 0, stream>>>(
            AO_bf, D, wo, D, P1, D, (size_t)T * D);
        rmsnorm_sum_kernel<NP_O, true><<<T, 256, 0, stream>>>(
            X, P1, ffn_norm + (size_t)l * D, Hn_bf);
        // GU + silu epilogue: 704 blocks, last block per ct reduces+silus
        gemm_gu_silu_kernel<<<dim3(F / 64, NP_G, 2), 512, 0, stream>>>(
            Hn_bf, wg, wu, P3, Gact, cntG);
        // Wd partials: K=2816 split 22x128 -> 352 blocks x 8 waves
        gemm64_kernel<<<dim3(D / 64, NP_D), 512, 0, stream>>>(
            Gact, F, wd, D, P2, D, (size_t)T * D);
    }

    // final: xl = rmsnorm(X[127] + sum P2[c][127]) * norm_out (fp32)
    rmsnorm_sum_kernel<NP_D, false><<<1, 256, 0, stream>>>(
        X + (size_t)(T - 1) * D, P2 + (size_t)(T - 1) * D, norm_out, xl);
    logits_kernel<<<V / 4, 256, 0, stream>>>(emb, xl, out);
}

// Round 17
// 667.111 us; speedup vs baseline: 4.2196x; 4.2196x over previous
//
#include <hip/hip_runtime.h>
#include <hip/hip_bf16.h>
#include <math.h>

namespace {
constexpr int V = 32000, D = 1024, L = 8, H = 16, T = 128, F = 2816, DH = 64;
constexpr float EPS = 1e-5f;
constexpr float SCALE = 0.125f; // 1/sqrt(DH)
constexpr int QKVN = 3 * D;     // 3072
constexpr int GUN  = 2 * F;     // 5632
constexpr int NP_Q = 8;         // QKV split-K chunks (CH=128)
constexpr int NP_O = 8;         // O-proj chunks (CH=128)
constexpr int NP_G = 8;         // GU chunks (CH=128)
constexpr int NP_D = 22;        // Wd chunks (K=2816 = 22*128)
}

typedef __attribute__((ext_vector_type(8))) short short8;
typedef __attribute__((ext_vector_type(4))) float f32x4;

__device__ __forceinline__ unsigned short f2bf(float x) {
    union { float f; unsigned u; } v; v.f = x;
    unsigned r = v.u + 0x7FFFu + ((v.u >> 16) & 1u);
    return (unsigned short)(r >> 16);
}

// ---------------- Embedding gather + RoPE tables (fused) ----------------
__global__ void embed_rope_kernel(const int* __restrict__ ids, const float* __restrict__ emb,
                                  float* __restrict__ X,
                                  float* __restrict__ cosT, float* __restrict__ sinT) {
    int t = blockIdx.x, tid = threadIdx.x;
    int id = ids[t];
    ((float4*)(X + (size_t)t * D))[tid] = ((const float4*)(emb + (size_t)id * D))[tid];
    if (tid < 32) {
        float inv = powf(10000.0f, -(2.0f * (float)tid) / (float)DH);
        float ang = (float)t * inv;
        cosT[t * 32 + tid] = cosf(ang);
        sinT[t * 32 + tid] = sinf(ang);
    }
}

// ---------------- RMSNorm + unrolled partial-sum residual update ----------------
template<int NP, bool BF16OUT>
__launch_bounds__(256)
__global__ void rmsnorm_sum_kernel(float* __restrict__ X, const float* __restrict__ P,
                                   const float* __restrict__ w, void* __restrict__ Y) {
    int t = blockIdx.x, tid = threadIdx.x;
    float4 xv = ((float4*)(X + (size_t)t * D))[tid];
    #pragma unroll
    for (int c = 0; c < NP; ++c) {
        float4 pv = ((const float4*)(P + ((size_t)c * T + t) * D))[tid];
        xv.x += pv.x; xv.y += pv.y; xv.z += pv.z; xv.w += pv.w;
    }
    if (NP) ((float4*)(X + (size_t)t * D))[tid] = xv;
    float s = xv.x * xv.x + xv.y * xv.y + xv.z * xv.z + xv.w * xv.w;
    for (int o = 32; o >= 1; o >>= 1) s += __shfl_xor(s, o);
    __shared__ float red[4];
    if ((tid & 63) == 0) red[tid >> 6] = s;
    __syncthreads();
    float tot = red[0] + red[1] + red[2] + red[3];
    float r = rsqrtf(tot / (float)D + EPS);
    float4 wv = ((const float4*)w)[tid];
    if (BF16OUT) {
        ushort4 y;
        y.x = f2bf(xv.x * r * wv.x); y.y = f2bf(xv.y * r * wv.y);
        y.z = f2bf(xv.z * r * wv.z); y.w = f2bf(xv.w * r * wv.w);
        ((ushort4*)((unsigned short*)Y + (size_t)t * D))[tid] = y;
    } else {
        float4 y;
        y.x = xv.x * r * wv.x; y.y = xv.y * r * wv.y;
        y.z = xv.z * r * wv.z; y.w = xv.w * r * wv.w;
        ((float4*)((float*)Y + (size_t)t * D))[tid] = y;
    }
}

// ---------------- 64-col staged MFMA GEMM, fp32 [K][N] weights, split-K ----------------
// (round-11 proven) 512 threads / 8 waves: wave = (M-half mh) x (col-group cg).
template<int CH>
__launch_bounds__(512)
__global__ void gemm64_kernel(const unsigned short* __restrict__ A, int lda,
                              const float* __restrict__ W0, const float* __restrict__ W1,
                              const float* __restrict__ W2, int ldw,
                              float* __restrict__ out, int ldo, int zColOff,
                              size_t chunkStride) {
    constexpr int STAGES = CH / 128;
    constexpr int LSTR = 136;
    __shared__ unsigned short Bst[2][64 * LSTR];
    const float* W = blockIdx.z == 0 ? W0 : (blockIdx.z == 1 ? W1 : W2);
    const int tid = threadIdx.x;
    const int wave = tid >> 6, lane = tid & 63;
    const int cg = wave & 3, mh = wave >> 2;
    const int n0 = blockIdx.x * 64;
    const int k0 = blockIdx.y * CH;
    const int sc = tid & 63;
    const int so = tid >> 6;  // 0..7
    const float* wCol = W + (size_t)k0 * ldw + n0 + sc;
    unsigned short* wp = &Bst[0][sc * LSTR];
    const int lrow = lane & 15;
    const int lqo = lane >> 4;
    const unsigned short* aB = A + (size_t)(mh * 64 + lrow) * lda + k0 + lqo * 8;
    const unsigned short* bRd = &Bst[0][(cg * 16 + lrow) * LSTR + lqo * 8];
    f32x4 acc[4] = {};
    float pre[16];
    auto ldst = [&](int s) {
        #pragma unroll
        for (int p = 0; p < 2; ++p) {
            const float* src = wCol + (size_t)(s * 128 + (so * 2 + p) * 8) * ldw;
            #pragma unroll
            for (int j = 0; j < 8; ++j) pre[p * 8 + j] = src[(size_t)j * ldw];
        }
    };
    auto wrst = [&](int buf) {
        #pragma unroll
        for (int p = 0; p < 2; ++p) {
            short8 bv;
            #pragma unroll
            for (int j = 0; j < 8; ++j) bv[j] = (short)f2bf(pre[p * 8 + j]);
            *(short8*)(wp + buf * (64 * LSTR) + (so * 2 + p) * 8) = bv;
        }
    };
    ldst(0);
    wrst(0);
    __syncthreads();
    #pragma unroll
    for (int s = 0; s < STAGES; ++s) {
        if (s + 1 < STAGES) ldst(s + 1);
        const unsigned short* rd = bRd + (s & 1) * (64 * LSTR);
        #pragma unroll
        for (int ks = 0; ks < 4; ++ks) {
            short8 b = *(const short8*)(rd + ks * 32);
            #pragma unroll
            for (int mf = 0; mf < 4; ++mf) {
                short8 a = *(const short8*)(aB + (size_t)(mf * 16) * lda + s * 128 + ks * 32);
                acc[mf] = __builtin_amdgcn_mfma_f32_16x16x32_bf16(a, b, acc[mf], 0, 0, 0);
            }
        }
        if (s + 1 < STAGES) {
            __syncthreads();
            wrst((s + 1) & 1);
            __syncthreads();
        }
    }
    const int col = zColOff * blockIdx.z + n0 + cg * 16 + lrow;
    float* op = out + blockIdx.y * chunkStride;
    #pragma unroll
    for (int mf = 0; mf < 4; ++mf) {
        int r0 = mh * 64 + mf * 16 + lqo * 4;
        #pragma unroll
        for (int r = 0; r < 4; ++r)
            op[(size_t)(r0 + r) * ldo + col] = acc[mf][r];
    }
}

// ---------------- QKV partial reduce + RoPE -> Qr,Vr [T][D]; K TRANSPOSED [H][DH][T] ----
__launch_bounds__(256)
__global__ void rope_reduce_kernel(const float* __restrict__ P,
                                   const float* __restrict__ cosT, const float* __restrict__ sinT,
                                   float* __restrict__ Qr, float* __restrict__ KrT,
                                   float* __restrict__ Vr) {
    int t = blockIdx.x, tid = threadIdx.x;
    int d0 = tid * 4;
    float4 q = {0.f, 0.f, 0.f, 0.f}, k = q, v = q;
    #pragma unroll
    for (int c = 0; c < NP_Q; ++c) {
        const float* base = P + ((size_t)c * T + t) * QKVN;
        float4 a = ((const float4*)base)[tid];
        float4 b = ((const float4*)(base + D))[tid];
        float4 w = ((const float4*)(base + 2 * D))[tid];
        q.x += a.x; q.y += a.y; q.z += a.z; q.w += a.w;
        k.x += b.x; k.y += b.y; k.z += b.z; k.w += b.w;
        v.x += w.x; v.y += w.y; v.z += w.z; v.w += w.w;
    }
    float4 c4 = *(const float4*)(cosT + t * 32 + (d0 & 31));
    float4 s4 = *(const float4*)(sinT + t * 32 + (d0 & 31));
    float sgn = (d0 & 32) ? 1.f : -1.f;
    float4 qp, kp;
    qp.x = __shfl_xor(q.x, 8); qp.y = __shfl_xor(q.y, 8);
    qp.z = __shfl_xor(q.z, 8); qp.w = __shfl_xor(q.w, 8);
    kp.x = __shfl_xor(k.x, 8); kp.y = __shfl_xor(k.y, 8);
    kp.z = __shfl_xor(k.z, 8); kp.w = __shfl_xor(k.w, 8);
    float4 qo, ko;
    qo.x = q.x * c4.x + sgn * qp.x * s4.x; qo.y = q.y * c4.y + sgn * qp.y * s4.y;
    qo.z = q.z * c4.z + sgn * qp.z * s4.z; qo.w = q.w * c4.w + sgn * qp.w * s4.w;
    ko.x = k.x * c4.x + sgn * kp.x * s4.x; ko.y = k.y * c4.y + sgn * kp.y * s4.y;
    ko.z = k.z * c4.z + sgn * kp.z * s4.z; ko.w = k.w * c4.w + sgn * kp.w * s4.w;
    *(float4*)(Qr + (size_t)t * D + d0) = qo;
    *(float4*)(Vr + (size_t)t * D + d0) = v;
    // K transposed: KrT[d][t], d global in [0,D)  (== [h][dh][t] since D = H*DH)
    KrT[(size_t)(d0 + 0) * T + t] = ko.x;
    KrT[(size_t)(d0 + 1) * T + t] = ko.y;
    KrT[(size_t)(d0 + 2) * T + t] = ko.z;
    KrT[(size_t)(d0 + 3) * T + t] = ko.w;
}

// ---------------- Causal attention: 4 heads/block, coalesced K^T scores ----------------
__launch_bounds__(256)
__global__ void attn_kernel(const float* __restrict__ Q, const float* __restrict__ KrT,
                            const float* __restrict__ Vc, unsigned short* __restrict__ AO) {
    int t = blockIdx.x;
    int wave = threadIdx.x >> 6, lane = threadIdx.x & 63;
    int h = blockIdx.y * 4 + wave;
    __shared__ float qs[4][64];
    __shared__ float ps[4][128];
    float* q = qs[wave];
    float* p = ps[wave];
    q[lane] = Q[(size_t)t * D + h * DH + lane];
    __syncthreads();
    // scores: lane = key j0 (and j1 = lane+64); K^T rows are lane-consecutive
    int j0 = lane, j1 = lane + 64;
    const float* kr = KrT + (size_t)h * DH * T;
    float s0 = 0.f, s1 = 0.f;
    #pragma unroll
    for (int d = 0; d < DH; ++d) {
        float qd = q[d];
        const float* krow = kr + (size_t)d * T;
        s0 = fmaf(qd, krow[j0], s0);
        s1 = fmaf(qd, krow[j1], s1);
    }
    s0 = (j0 <= t) ? s0 * SCALE : -1e30f;
    s1 = (j1 <= t) ? s1 * SCALE : -1e30f;
    float m = fmaxf(s0, s1);
    for (int o = 32; o >= 1; o >>= 1) m = fmaxf(m, __shfl_xor(m, o));
    float e0 = (j0 <= t) ? __expf(s0 - m) : 0.f;
    float e1 = (j1 <= t) ? __expf(s1 - m) : 0.f;
    float sum = e0 + e1;
    for (int o = 32; o >= 1; o >>= 1) sum += __shfl_xor(sum, o);
    float inv = 1.f / sum;
    p[j0] = e0 * inv;   // p[j] = 0 for j > t -> fixed-trip PV exact
    p[j1] = e1 * inv;
    __syncthreads();
    const float* vcol = Vc + h * DH + lane;
    float a0 = 0.f, a1 = 0.f, a2 = 0.f, a3 = 0.f;
    #pragma unroll
    for (int j = 0; j < T; j += 4) {
        a0 = fmaf(p[j],     vcol[(size_t)(j)     * D], a0);
        a1 = fmaf(p[j + 1], vcol[(size_t)(j + 1) * D], a1);
        a2 = fmaf(p[j + 2], vcol[(size_t)(j + 2) * D], a2);
        a3 = fmaf(p[j + 3], vcol[(size_t)(j + 3) * D], a3);
    }
    AO[(size_t)t * D + h * DH + lane] = f2bf((a0 + a1) + (a2 + a3));
}

// ---------------- GU partial reduce + silu(g)*u -> Gact bf16 [T][F] ----------------
__launch_bounds__(256)
__global__ void silu_reduce_kernel(const float* __restrict__ P,
                                   unsigned short* __restrict__ Gact) {
    int t = blockIdx.y;
    int f = blockIdx.x * 256 + threadIdx.x;
    float g = 0.f, u = 0.f;
    #pragma unroll
    for (int c = 0; c < NP_G; ++c) {
        const float* base = P + ((size_t)c * T + t) * GUN;
        g += base[f];
        u += base[F + f];
    }
    Gact[(size_t)t * F + f] = f2bf(g / (1.f + __expf(-g)) * u);
}

// ---------------- logits: out[v] = emb[v,:] . xl ----------------
__global__ void logits_kernel(const float* __restrict__ emb, const float* __restrict__ xl,
                              float* __restrict__ out) {
    __shared__ float x[D];
    int tid = threadIdx.x;
    ((float4*)x)[tid] = ((const float4*)xl)[tid];
    __syncthreads();
    int row = blockIdx.x * 4 + (tid >> 6);
    int lane = tid & 63;
    const float4* e4 = (const float4*)(emb + (size_t)row * D);
    const float4* x4 = (const float4*)x;
    float s = 0.f;
    #pragma unroll
    for (int k = lane; k < D / 4; k += 64) {
        float4 ev = e4[k], xv = x4[k];
        s += ev.x * xv.x + ev.y * xv.y + ev.z * xv.z + ev.w * xv.w;
    }
    for (int o = 32; o >= 1; o >>= 1) s += __shfl_xor(s, o);
    if (lane == 0) out[row] = s;
}

extern "C" void kernel_launch(void* const* d_in, const int* in_sizes, int n_in,
                              void* d_out, int out_size, void* d_ws, size_t ws_size,
                              hipStream_t stream) {
    const int*   ids = (const int*)d_in[0];
    const float* emb = (const float*)d_in[1];
    const float* Wq  = (const float*)d_in[2];
    const float* Wk  = (const float*)d_in[3];
    const float* Wv  = (const float*)d_in[4];
    const float* Wo  = (const float*)d_in[5];
    const float* Wg  = (const float*)d_in[6];
    const float* Wu  = (const float*)d_in[7];
    const float* Wd  = (const float*)d_in[8];
    const float* attn_norm = (const float*)d_in[9];
    const float* ffn_norm  = (const float*)d_in[10];
    const float* norm_out  = (const float*)d_in[11];
    float* out = (float*)d_out;

    size_t off = 0;
    auto alloc = [&](size_t bytes) {
        void* p = (char*)d_ws + off;
        off += (bytes + 255) & ~(size_t)255;
        return p;
    };
    float*          X     = (float*)alloc((size_t)T * D * 4);
    float*          P0    = (float*)alloc((size_t)NP_Q * T * QKVN * 4);  // QKV partials
    float*          P1    = (float*)alloc((size_t)NP_O * T * D * 4);     // O-proj partials
    float*          P2    = (float*)alloc((size_t)NP_D * T * D * 4);     // Wd partials
    float*          P3    = (float*)alloc((size_t)NP_G * T * GUN * 4);   // GU partials
    float*          Qr    = (float*)alloc((size_t)T * D * 4);
    float*          KrT   = (float*)alloc((size_t)T * D * 4);
    float*          Vr    = (float*)alloc((size_t)T * D * 4);
    float*          cosT  = (float*)alloc((size_t)T * 32 * 4);
    float*          sinT  = (float*)alloc((size_t)T * 32 * 4);
    float*          xl    = (float*)alloc((size_t)D * 4);
    unsigned short* Hn_bf = (unsigned short*)alloc((size_t)T * D * 2);
    unsigned short* AO_bf = (unsigned short*)alloc((size_t)T * D * 2);
    unsigned short* Gact  = (unsigned short*)alloc((size_t)T * F * 2);
    (void)ws_size;

    embed_rope_kernel<<<T, 256, 0, stream>>>(ids, emb, X, cosT, sinT);

    for (int l = 0; l < L; ++l) {
        const float* wq = Wq + (size_t)l * D * D;
        const float* wk = Wk + (size_t)l * D * D;
        const float* wv = Wv + (size_t)l * D * D;
        const float* wo = Wo + (size_t)l * D * D;
        const float* wg = Wg + (size_t)l * D * F;
        const float* wu = Wu + (size_t)l * D * F;
        const float* wd = Wd + (size_t)l * F * D;

        // X += prev Wd partials; Hn = rmsnorm(X)*attn_norm (bf16)
        if (l == 0)
            rmsnorm_sum_kernel<0, true><<<T, 256, 0, stream>>>(
                X, P2, attn_norm + (size_t)l * D, Hn_bf);
        else
            rmsnorm_sum_kernel<NP_D, true><<<T, 256, 0, stream>>>(
                X, P2, attn_norm + (size_t)l * D, Hn_bf);
        // QKV partials: 64-col, K=1024 split 8x128, z in {q,k,v} -> 384 blocks x 8 waves
        gemm64_kernel<128><<<dim3(D / 64, NP_Q, 3), 512, 0, stream>>>(
            Hn_bf, D, wq, wk, wv, D, P0, QKVN, D, (size_t)T * QKVN);
        rope_reduce_kernel<<<T, 256, 0, stream>>>(P0, cosT, sinT, Qr, KrT, Vr);
        // attention: 4 heads/block, K^T coalesced scores, fixed-trip PV -> 512 blocks
        attn_kernel<<<dim3(T, H / 4), 256, 0, stream>>>(Qr, KrT, Vr, AO_bf);
        // O-proj partials: K=1024 split 8x128 -> 128 blocks x 8 waves
        gemm64_kernel<128><<<dim3(D / 64, NP_O, 1), 512, 0, stream>>>(
            AO_bf, D, wo, wo, wo, D, P1, D, 0, (size_t)T * D);
        rmsnorm_sum_kernel<NP_O, true><<<T, 256, 0, stream>>>(
            X, P1, ffn_norm + (size_t)l * D, Hn_bf);
        // GU partials: K=1024 split 8x128, z in {g,u} -> 704 blocks x 8 waves
        gemm64_kernel<128><<<dim3(F / 64, NP_G, 2), 512, 0, stream>>>(
            Hn_bf, D, wg, wu, wu, F, P3, GUN, F, (size_t)T * GUN);
        silu_reduce_kernel<<<dim3(F / 256, T), 256, 0, stream>>>(P3, Gact);
        // Wd partials: K=2816 split 22x128 -> 352 blocks x 8 waves
        gemm64_kernel<128><<<dim3(D / 64, NP_D, 1), 512, 0, stream>>>(
            Gact, F, wd, wd, wd, D, P2, D, 0, (size_t)T * D);
    }

    // final: xl = rmsnorm(X[127] + sum P2[c][127]) * norm_out (fp32)
    rmsnorm_sum_kernel<NP_D, false><<<1, 256, 0, stream>>>(
        X + (size_t)(T - 1) * D, P2 + (size_t)(T - 1) * D, norm_out, xl);
    logits_kernel<<<V / 4, 256, 0, stream>>>(emb, xl, out);
}

// Round 18
// 666.978 us; speedup vs baseline: 4.2205x; 1.0002x over previous
//
#include <hip/hip_runtime.h>
#include <hip/hip_bf16.h>
#include <math.h>

namespace {
constexpr int V = 32000, D = 1024, L = 8, H = 16, T = 128, F = 2816, DH = 64;
constexpr float EPS = 1e-5f;
constexpr float SCALE = 0.125f; // 1/sqrt(DH)
constexpr int QKVN = 3 * D;     // 3072
constexpr int GUN  = 2 * F;     // 5632
constexpr int NP_Q = 8;         // QKV split-K chunks (CH=128)
constexpr int NP_O = 8;         // O-proj chunks (CH=128)
constexpr int NP_G = 8;         // GU chunks (CH=128)
constexpr int NP_D = 22;        // Wd chunks (K=2816 = 22*128)
}

typedef __attribute__((ext_vector_type(8))) short short8;
typedef __attribute__((ext_vector_type(4))) float f32x4;

__device__ __forceinline__ unsigned short f2bf(float x) {
    union { float f; unsigned u; } v; v.f = x;
    unsigned r = v.u + 0x7FFFu + ((v.u >> 16) & 1u);
    return (unsigned short)(r >> 16);
}

// ---------------- Embedding gather + RoPE tables (fused) ----------------
__global__ void embed_rope_kernel(const int* __restrict__ ids, const float* __restrict__ emb,
                                  float* __restrict__ X,
                                  float* __restrict__ cosT, float* __restrict__ sinT) {
    int t = blockIdx.x, tid = threadIdx.x;
    int id = ids[t];
    ((float4*)(X + (size_t)t * D))[tid] = ((const float4*)(emb + (size_t)id * D))[tid];
    if (tid < 32) {
        float inv = powf(10000.0f, -(2.0f * (float)tid) / (float)DH);
        float ang = (float)t * inv;
        cosT[t * 32 + tid] = cosf(ang);
        sinT[t * 32 + tid] = sinf(ang);
    }
}

// ---------------- RMSNorm + unrolled partial-sum residual update ----------------
template<int NP, bool BF16OUT>
__launch_bounds__(256)
__global__ void rmsnorm_sum_kernel(float* __restrict__ X, const float* __restrict__ P,
                                   const float* __restrict__ w, void* __restrict__ Y) {
    int t = blockIdx.x, tid = threadIdx.x;
    float4 xv = ((float4*)(X + (size_t)t * D))[tid];
    #pragma unroll
    for (int c = 0; c < NP; ++c) {
        float4 pv = ((const float4*)(P + ((size_t)c * T + t) * D))[tid];
        xv.x += pv.x; xv.y += pv.y; xv.z += pv.z; xv.w += pv.w;
    }
    if (NP) ((float4*)(X + (size_t)t * D))[tid] = xv;
    float s = xv.x * xv.x + xv.y * xv.y + xv.z * xv.z + xv.w * xv.w;
    for (int o = 32; o >= 1; o >>= 1) s += __shfl_xor(s, o);
    __shared__ float red[4];
    if ((tid & 63) == 0) red[tid >> 6] = s;
    __syncthreads();
    float tot = red[0] + red[1] + red[2] + red[3];
    float r = rsqrtf(tot / (float)D + EPS);
    float4 wv = ((const float4*)w)[tid];
    if (BF16OUT) {
        ushort4 y;
        y.x = f2bf(xv.x * r * wv.x); y.y = f2bf(xv.y * r * wv.y);
        y.z = f2bf(xv.z * r * wv.z); y.w = f2bf(xv.w * r * wv.w);
        ((ushort4*)((unsigned short*)Y + (size_t)t * D))[tid] = y;
    } else {
        float4 y;
        y.x = xv.x * r * wv.x; y.y = xv.y * r * wv.y;
        y.z = xv.z * r * wv.z; y.w = xv.w * r * wv.w;
        ((float4*)((float*)Y + (size_t)t * D))[tid] = y;
    }
}

// ---------------- 64-col staged MFMA GEMM, fp32 [K][N] weights, split-K ----------------
// (round-11 proven) 512 threads / 8 waves: wave = (M-half mh) x (col-group cg).
template<int CH>
__launch_bounds__(512)
__global__ void gemm64_kernel(const unsigned short* __restrict__ A, int lda,
                              const float* __restrict__ W0, const float* __restrict__ W1,
                              const float* __restrict__ W2, int ldw,
                              float* __restrict__ out, int ldo, int zColOff,
                              size_t chunkStride) {
    constexpr int STAGES = CH / 128;
    constexpr int LSTR = 136;
    __shared__ unsigned short Bst[2][64 * LSTR];
    const float* W = blockIdx.z == 0 ? W0 : (blockIdx.z == 1 ? W1 : W2);
    const int tid = threadIdx.x;
    const int wave = tid >> 6, lane = tid & 63;
    const int cg = wave & 3, mh = wave >> 2;
    const int n0 = blockIdx.x * 64;
    const int k0 = blockIdx.y * CH;
    const int sc = tid & 63;
    const int so = tid >> 6;  // 0..7
    const float* wCol = W + (size_t)k0 * ldw + n0 + sc;
    unsigned short* wp = &Bst[0][sc * LSTR];
    const int lrow = lane & 15;
    const int lqo = lane >> 4;
    const unsigned short* aB = A + (size_t)(mh * 64 + lrow) * lda + k0 + lqo * 8;
    const unsigned short* bRd = &Bst[0][(cg * 16 + lrow) * LSTR + lqo * 8];
    f32x4 acc[4] = {};
    float pre[16];
    auto ldst = [&](int s) {
        #pragma unroll
        for (int p = 0; p < 2; ++p) {
            const float* src = wCol + (size_t)(s * 128 + (so * 2 + p) * 8) * ldw;
            #pragma unroll
            for (int j = 0; j < 8; ++j) pre[p * 8 + j] = src[(size_t)j * ldw];
        }
    };
    auto wrst = [&](int buf) {
        #pragma unroll
        for (int p = 0; p < 2; ++p) {
            short8 bv;
            #pragma unroll
            for (int j = 0; j < 8; ++j) bv[j] = (short)f2bf(pre[p * 8 + j]);
            *(short8*)(wp + buf * (64 * LSTR) + (so * 2 + p) * 8) = bv;
        }
    };
    ldst(0);
    wrst(0);
    __syncthreads();
    #pragma unroll
    for (int s = 0; s < STAGES; ++s) {
        if (s + 1 < STAGES) ldst(s + 1);
        const unsigned short* rd = bRd + (s & 1) * (64 * LSTR);
        #pragma unroll
        for (int ks = 0; ks < 4; ++ks) {
            short8 b = *(const short8*)(rd + ks * 32);
            #pragma unroll
            for (int mf = 0; mf < 4; ++mf) {
                short8 a = *(const short8*)(aB + (size_t)(mf * 16) * lda + s * 128 + ks * 32);
                acc[mf] = __builtin_amdgcn_mfma_f32_16x16x32_bf16(a, b, acc[mf], 0, 0, 0);
            }
        }
        if (s + 1 < STAGES) {
            __syncthreads();
            wrst((s + 1) & 1);
            __syncthreads();
        }
    }
    const int col = zColOff * blockIdx.z + n0 + cg * 16 + lrow;
    float* op = out + blockIdx.y * chunkStride;
    #pragma unroll
    for (int mf = 0; mf < 4; ++mf) {
        int r0 = mh * 64 + mf * 16 + lqo * 4;
        #pragma unroll
        for (int r = 0; r < 4; ++r)
            op[(size_t)(r0 + r) * ldo + col] = acc[mf][r];
    }
}

// ---------------- QKV partial reduce + RoPE -> Qr,Vr [T][D]; K TRANSPOSED [H][DH][T] ----
__launch_bounds__(256)
__global__ void rope_reduce_kernel(const float* __restrict__ P,
                                   const float* __restrict__ cosT, const float* __restrict__ sinT,
                                   float* __restrict__ Qr, float* __restrict__ KrT,
                                   float* __restrict__ Vr) {
    int t = blockIdx.x, tid = threadIdx.x;
    int d0 = tid * 4;
    float4 q = {0.f, 0.f, 0.f, 0.f}, k = q, v = q;
    #pragma unroll
    for (int c = 0; c < NP_Q; ++c) {
        const float* base = P + ((size_t)c * T + t) * QKVN;
        float4 a = ((const float4*)base)[tid];
        float4 b = ((const float4*)(base + D))[tid];
        float4 w = ((const float4*)(base + 2 * D))[tid];
        q.x += a.x; q.y += a.y; q.z += a.z; q.w += a.w;
        k.x += b.x; k.y += b.y; k.z += b.z; k.w += b.w;
        v.x += w.x; v.y += w.y; v.z += w.z; v.w += w.w;
    }
    float4 c4 = *(const float4*)(cosT + t * 32 + (d0 & 31));
    float4 s4 = *(const float4*)(sinT + t * 32 + (d0 & 31));
    float sgn = (d0 & 32) ? 1.f : -1.f;
    float4 qp, kp;
    qp.x = __shfl_xor(q.x, 8); qp.y = __shfl_xor(q.y, 8);
    qp.z = __shfl_xor(q.z, 8); qp.w = __shfl_xor(q.w, 8);
    kp.x = __shfl_xor(k.x, 8); kp.y = __shfl_xor(k.y, 8);
    kp.z = __shfl_xor(k.z, 8); kp.w = __shfl_xor(k.w, 8);
    float4 qo, ko;
    qo.x = q.x * c4.x + sgn * qp.x * s4.x; qo.y = q.y * c4.y + sgn * qp.y * s4.y;
    qo.z = q.z * c4.z + sgn * qp.z * s4.z; qo.w = q.w * c4.w + sgn * qp.w * s4.w;
    ko.x = k.x * c4.x + sgn * kp.x * s4.x; ko.y = k.y * c4.y + sgn * kp.y * s4.y;
    ko.z = k.z * c4.z + sgn * kp.z * s4.z; ko.w = k.w * c4.w + sgn * kp.w * s4.w;
    *(float4*)(Qr + (size_t)t * D + d0) = qo;
    *(float4*)(Vr + (size_t)t * D + d0) = v;
    // K transposed: KrT[d][t], d global in [0,D)  (== [h][dh][t] since D = H*DH)
    KrT[(size_t)(d0 + 0) * T + t] = ko.x;
    KrT[(size_t)(d0 + 1) * T + t] = ko.y;
    KrT[(size_t)(d0 + 2) * T + t] = ko.z;
    KrT[(size_t)(d0 + 3) * T + t] = ko.w;
}

// ---------------- Causal attention: 4 heads/block, coalesced K^T scores ----------------
__launch_bounds__(256)
__global__ void attn_kernel(const float* __restrict__ Q, const float* __restrict__ KrT,
                            const float* __restrict__ Vc, unsigned short* __restrict__ AO) {
    int t = blockIdx.x;
    int wave = threadIdx.x >> 6, lane = threadIdx.x & 63;
    int h = blockIdx.y * 4 + wave;
    __shared__ float qs[4][64];
    __shared__ float ps[4][128];
    float* q = qs[wave];
    float* p = ps[wave];
    q[lane] = Q[(size_t)t * D + h * DH + lane];
    __syncthreads();
    // scores: lane = key j0 (and j1 = lane+64); K^T rows are lane-consecutive
    int j0 = lane, j1 = lane + 64;
    const float* kr = KrT + (size_t)h * DH * T;
    float s0 = 0.f, s1 = 0.f;
    #pragma unroll
    for (int d = 0; d < DH; ++d) {
        float qd = q[d];
        const float* krow = kr + (size_t)d * T;
        s0 = fmaf(qd, krow[j0], s0);
        s1 = fmaf(qd, krow[j1], s1);
    }
    s0 = (j0 <= t) ? s0 * SCALE : -1e30f;
    s1 = (j1 <= t) ? s1 * SCALE : -1e30f;
    float m = fmaxf(s0, s1);
    for (int o = 32; o >= 1; o >>= 1) m = fmaxf(m, __shfl_xor(m, o));
    float e0 = (j0 <= t) ? __expf(s0 - m) : 0.f;
    float e1 = (j1 <= t) ? __expf(s1 - m) : 0.f;
    float sum = e0 + e1;
    for (int o = 32; o >= 1; o >>= 1) sum += __shfl_xor(sum, o);
    float inv = 1.f / sum;
    p[j0] = e0 * inv;   // p[j] = 0 for j > t -> fixed-trip PV exact
    p[j1] = e1 * inv;
    __syncthreads();
    const float* vcol = Vc + h * DH + lane;
    float a0 = 0.f, a1 = 0.f, a2 = 0.f, a3 = 0.f;
    #pragma unroll
    for (int j = 0; j < T; j += 4) {
        a0 = fmaf(p[j],     vcol[(size_t)(j)     * D], a0);
        a1 = fmaf(p[j + 1], vcol[(size_t)(j + 1) * D], a1);
        a2 = fmaf(p[j + 2], vcol[(size_t)(j + 2) * D], a2);
        a3 = fmaf(p[j + 3], vcol[(size_t)(j + 3) * D], a3);
    }
    AO[(size_t)t * D + h * DH + lane] = f2bf((a0 + a1) + (a2 + a3));
}

// ---------------- GU partial reduce + silu(g)*u -> Gact bf16 [T][F] ----------------
__launch_bounds__(256)
__global__ void silu_reduce_kernel(const float* __restrict__ P,
                                   unsigned short* __restrict__ Gact) {
    int t = blockIdx.y;
    int f = blockIdx.x * 256 + threadIdx.x;
    float g = 0.f, u = 0.f;
    #pragma unroll
    for (int c = 0; c < NP_G; ++c) {
        const float* base = P + ((size_t)c * T + t) * GUN;
        g += base[f];
        u += base[F + f];
    }
    Gact[(size_t)t * F + f] = f2bf(g / (1.f + __expf(-g)) * u);
}

// ---------------- logits: out[v] = emb[v,:] . xl ----------------
__global__ void logits_kernel(const float* __restrict__ emb, const float* __restrict__ xl,
                              float* __restrict__ out) {
    __shared__ float x[D];
    int tid = threadIdx.x;
    ((float4*)x)[tid] = ((const float4*)xl)[tid];
    __syncthreads();
    int row = blockIdx.x * 4 + (tid >> 6);
    int lane = tid & 63;
    const float4* e4 = (const float4*)(emb + (size_t)row * D);
    const float4* x4 = (const float4*)x;
    float s = 0.f;
    #pragma unroll
    for (int k = lane; k < D / 4; k += 64) {
        float4 ev = e4[k], xv = x4[k];
        s += ev.x * xv.x + ev.y * xv.y + ev.z * xv.z + ev.w * xv.w;
    }
    for (int o = 32; o >= 1; o >>= 1) s += __shfl_xor(s, o);
    if (lane == 0) out[row] = s;
}

extern "C" void kernel_launch(void* const* d_in, const int* in_sizes, int n_in,
                              void* d_out, int out_size, void* d_ws, size_t ws_size,
                              hipStream_t stream) {
    const int*   ids = (const int*)d_in[0];
    const float* emb = (const float*)d_in[1];
    const float* Wq  = (const float*)d_in[2];
    const float* Wk  = (const float*)d_in[3];
    const float* Wv  = (const float*)d_in[4];
    const float* Wo  = (const float*)d_in[5];
    const float* Wg  = (const float*)d_in[6];
    const float* Wu  = (const float*)d_in[7];
    const float* Wd  = (const float*)d_in[8];
    const float* attn_norm = (const float*)d_in[9];
    const float* ffn_norm  = (const float*)d_in[10];
    const float* norm_out  = (const float*)d_in[11];
    float* out = (float*)d_out;

    size_t off = 0;
    auto alloc = [&](size_t bytes) {
        void* p = (char*)d_ws + off;
        off += (bytes + 255) & ~(size_t)255;
        return p;
    };
    float*          X     = (float*)alloc((size_t)T * D * 4);
    float*          P0    = (float*)alloc((size_t)NP_Q * T * QKVN * 4);  // QKV partials
    float*          P1    = (float*)alloc((size_t)NP_O * T * D * 4);     // O-proj partials
    float*          P2    = (float*)alloc((size_t)NP_D * T * D * 4);     // Wd partials
    float*          P3    = (float*)alloc((size_t)NP_G * T * GUN * 4);   // GU partials
    float*          Qr    = (float*)alloc((size_t)T * D * 4);
    float*          KrT   = (float*)alloc((size_t)T * D * 4);
    float*          Vr    = (float*)alloc((size_t)T * D * 4);
    float*          cosT  = (float*)alloc((size_t)T * 32 * 4);
    float*          sinT  = (float*)alloc((size_t)T * 32 * 4);
    float*          xl    = (float*)alloc((size_t)D * 4);
    unsigned short* Hn_bf = (unsigned short*)alloc((size_t)T * D * 2);
    unsigned short* AO_bf = (unsigned short*)alloc((size_t)T * D * 2);
    unsigned short* Gact  = (unsigned short*)alloc((size_t)T * F * 2);
    (void)ws_size;

    embed_rope_kernel<<<T, 256, 0, stream>>>(ids, emb, X, cosT, sinT);

    for (int l = 0; l < L; ++l) {
        const float* wq = Wq + (size_t)l * D * D;
        const float* wk = Wk + (size_t)l * D * D;
        const float* wv = Wv + (size_t)l * D * D;
        const float* wo = Wo + (size_t)l * D * D;
        const float* wg = Wg + (size_t)l * D * F;
        const float* wu = Wu + (size_t)l * D * F;
        const float* wd = Wd + (size_t)l * F * D;

        // X += prev Wd partials; Hn = rmsnorm(X)*attn_norm (bf16)
        if (l == 0)
            rmsnorm_sum_kernel<0, true><<<T, 256, 0, stream>>>(
                X, P2, attn_norm + (size_t)l * D, Hn_bf);
        else
            rmsnorm_sum_kernel<NP_D, true><<<T, 256, 0, stream>>>(
                X, P2, attn_norm + (size_t)l * D, Hn_bf);
        // QKV partials: 64-col, K=1024 split 8x128, z in {q,k,v} -> 384 blocks x 8 waves
        gemm64_kernel<128><<<dim3(D / 64, NP_Q, 3), 512, 0, stream>>>(
            Hn_bf, D, wq, wk, wv, D, P0, QKVN, D, (size_t)T * QKVN);
        rope_reduce_kernel<<<T, 256, 0, stream>>>(P0, cosT, sinT, Qr, KrT, Vr);
        // attention: 4 heads/block, K^T coalesced scores, fixed-trip PV -> 512 blocks
        attn_kernel<<<dim3(T, H / 4), 256, 0, stream>>>(Qr, KrT, Vr, AO_bf);
        // O-proj partials: K=1024 split 8x128 -> 128 blocks x 8 waves
        gemm64_kernel<128><<<dim3(D / 64, NP_O, 1), 512, 0, stream>>>(
            AO_bf, D, wo, wo, wo, D, P1, D, 0, (size_t)T * D);
        rmsnorm_sum_kernel<NP_O, true><<<T, 256, 0, stream>>>(
            X, P1, ffn_norm + (size_t)l * D, Hn_bf);
        // GU partials: K=1024 split 8x128, z in {g,u} -> 704 blocks x 8 waves
        gemm64_kernel<128><<<dim3(F / 64, NP_G, 2), 512, 0, stream>>>(
            Hn_bf, D, wg, wu, wu, F, P3, GUN, F, (size_t)T * GUN);
        silu_reduce_kernel<<<dim3(F / 256, T), 256, 0, stream>>>(P3, Gact);
        // Wd partials: K=2816 split 22x128 -> 352 blocks x 8 waves
        gemm64_kernel<128><<<dim3(D / 64, NP_D, 1), 512, 0, stream>>>(
            Gact, F, wd, wd, wd, D, P2, D, 0, (size_t)T * D);
    }

    // final: xl = rmsnorm(X[127] + sum P2[c][127]) * norm_out (fp32)
    rmsnorm_sum_kernel<NP_D, false><<<1, 256, 0, stream>>>(
        X + (size_t)(T - 1) * D, P2 + (size_t)(T - 1) * D, norm_out, xl);
    logits_kernel<<<V / 4, 256, 0, stream>>>(emb, xl, out);
}